// Round 8
// baseline (52.882 us; speedup 1.0000x reference)
//
#include <hip/hip_runtime.h>

// PCEN [B=64,C=128,T=4000] f32: M_t = 0.975 M_{t-1} + 0.025 x_t (M_{-1}=0);
//   y = sqrt(x * (M+1e-6)^-0.98 + 2) - sqrt(2)
// R8 = R7 (52.5us) with ONE change: prefetch depth 3 (tiles t+1..t+3 in flight
// during compute of tile t) to raise per-wave memory-level parallelism.
// Loop fully unrolled (NFULL=15) so the 3 rotating f32x4 buffers stay in
// registers (static indexing). Everything else identical to R7: DPP weighted
// scan, E=(I-b)/K carry, EPL=4, tile=256, 1 wave/row, plain float4 stores,
// 2048 blocks x 256.

#define T_LEN 4000
#define TILE  256
#define NFULL (T_LEN / TILE)            // 15 full tiles
#define TAILL ((T_LEN - NFULL*TILE)/4)  // 40 active lanes in 160-elem tail

typedef float f32x4 __attribute__((ext_vector_type(4)));

constexpr double dpow(double b, int e) { double r = 1.0; for (int i = 0; i < e; ++i) r *= b; return r; }

// mov_dpp with old=0: masked-out / OOB lanes read 0.0f
template<int CTRL, int RMASK, bool BC>
__device__ __forceinline__ float dpp0(float x) {
    return __int_as_float(__builtin_amdgcn_update_dpp(
        0, __float_as_int(x), CTRL, RMASK, 0xf, BC));
}

__device__ __forceinline__ float pcen_y(float x, float M) {
    float p = __builtin_amdgcn_exp2f(-0.98f * __builtin_amdgcn_logf(M + 1e-6f));
    return sqrtf(fmaf(x, p, 2.0f)) - 1.41421356237309515f;
}

__global__ __launch_bounds__(256) void pcen_kernel(const float* __restrict__ x,
                                                   float* __restrict__ y) {
    const int wid  = threadIdx.x >> 6;
    const int lane = threadIdx.x & 63;
    const int row  = blockIdx.x * 4 + wid;

    const float S   = 0.025f, OMS = 0.975f;
    const float K1   = (float)dpow(0.975, 4);        // K = 0.975^4
    const float K2   = (float)dpow(0.975, 8);
    const float K4   = (float)dpow(0.975, 16);
    const float K8   = (float)dpow(0.975, 32);
    const float KT   = (float)dpow(0.975, 256);      // whole-tile decay
    const float invK = (float)(1.0 / dpow(0.975, 4));

    const float L2K = -0.14610279749811041f;         // log2(0.975^4)
    const float c  = __builtin_amdgcn_exp2f((float)lane * L2K);
    const float m1 = __builtin_amdgcn_exp2f((float)((lane & 15) + 1) * L2K);
    const float m2 = __builtin_amdgcn_exp2f((float)((lane & 31) + 1) * L2K);

    const float* __restrict__ xr = x + (size_t)row * T_LEN;
    float*       __restrict__ yr = y + (size_t)row * T_LEN;
    const int l4 = lane * 4;

    float M0 = 0.0f;

    // prefetch pipeline: 3 tiles in flight
    f32x4 p0 = *reinterpret_cast<const f32x4*>(xr + 0 * TILE + l4);
    f32x4 p1 = *reinterpret_cast<const f32x4*>(xr + 1 * TILE + l4);
    f32x4 p2 = *reinterpret_cast<const f32x4*>(xr + 2 * TILE + l4);

    #pragma unroll
    for (int t = 0; t < NFULL; ++t) {
        const f32x4 v = p0;
        p0 = p1; p1 = p2;                 // register rotation (renamed by unroll)
        if (t + 3 < NFULL)
            p2 = *reinterpret_cast<const f32x4*>(xr + (t + 3) * TILE + l4);

        // lane-local affine offset from M=0
        float b = S * v.x;
        b = fmaf(S, v.y, OMS * b);
        b = fmaf(S, v.z, OMS * b);
        b = fmaf(S, v.w, OMS * b);

        // 64-lane weighted inclusive scan (DPP, all in VALU pipe)
        float I = b, tv;
        tv = dpp0<0x111, 0xf, true >(I);  I = fmaf(K1, tv, I);   // row_shr:1
        tv = dpp0<0x112, 0xf, true >(I);  I = fmaf(K2, tv, I);   // row_shr:2
        tv = dpp0<0x114, 0xf, true >(I);  I = fmaf(K4, tv, I);   // row_shr:4
        tv = dpp0<0x118, 0xf, true >(I);  I = fmaf(K8, tv, I);   // row_shr:8
        tv = dpp0<0x142, 0xa, false>(I);  I = fmaf(m1, tv, I);   // bcast15 -> rows 1,3
        tv = dpp0<0x143, 0xc, false>(I);  I = fmaf(m2, tv, I);   // bcast31 -> rows 2,3

        // exclusive carry-in E = (I-b)/K, then replay 4 elements
        float M = fmaf(c, M0, (I - b) * invK);
        f32x4 o;
        M = fmaf(S, v.x, OMS * M);  o.x = pcen_y(v.x, M);
        M = fmaf(S, v.y, OMS * M);  o.y = pcen_y(v.y, M);
        M = fmaf(S, v.z, OMS * M);  o.z = pcen_y(v.z, M);
        M = fmaf(S, v.w, OMS * M);  o.w = pcen_y(v.w, M);
        *reinterpret_cast<f32x4*>(yr + t * TILE + l4) = o;

        // cross-tile carry: inclusive total of lane 63
        const float Ilast = __int_as_float(
            __builtin_amdgcn_readlane(__float_as_int(I), 63));
        M0 = fmaf(KT, M0, Ilast);
    }

    // tail: 160 elements, lanes 0..39 active
    {
        const bool act = lane < TAILL;
        f32x4 v = {0.f, 0.f, 0.f, 0.f};
        if (act) v = *reinterpret_cast<const f32x4*>(xr + NFULL * TILE + l4);

        float b = S * v.x;
        b = fmaf(S, v.y, OMS * b);
        b = fmaf(S, v.z, OMS * b);
        b = fmaf(S, v.w, OMS * b);

        float I = b, tv;
        tv = dpp0<0x111, 0xf, true >(I);  I = fmaf(K1, tv, I);
        tv = dpp0<0x112, 0xf, true >(I);  I = fmaf(K2, tv, I);
        tv = dpp0<0x114, 0xf, true >(I);  I = fmaf(K4, tv, I);
        tv = dpp0<0x118, 0xf, true >(I);  I = fmaf(K8, tv, I);
        tv = dpp0<0x142, 0xa, false>(I);  I = fmaf(m1, tv, I);
        tv = dpp0<0x143, 0xc, false>(I);  I = fmaf(m2, tv, I);

        float M = fmaf(c, M0, (I - b) * invK);
        f32x4 o;
        M = fmaf(S, v.x, OMS * M);  o.x = pcen_y(v.x, M);
        M = fmaf(S, v.y, OMS * M);  o.y = pcen_y(v.y, M);
        M = fmaf(S, v.z, OMS * M);  o.z = pcen_y(v.z, M);
        M = fmaf(S, v.w, OMS * M);  o.w = pcen_y(v.w, M);
        if (act)
            *reinterpret_cast<f32x4*>(yr + NFULL * TILE + l4) = o;
    }
}

extern "C" void kernel_launch(void* const* d_in, const int* in_sizes, int n_in,
                              void* d_out, int out_size, void* d_ws, size_t ws_size,
                              hipStream_t stream) {
    const float* x = (const float*)d_in[0];
    float* y       = (float*)d_out;
    pcen_kernel<<<8192 / 4, 256, 0, stream>>>(x, y);  // 2048 blocks, 4 rows/block
}

// Round 9
// 45.528 us; speedup vs baseline: 1.1615x; 1.1615x over previous
//
#include <hip/hip_runtime.h>

// PCEN [B=64,C=128,T=4000] f32: M_t = 0.975 M_{t-1} + 0.025 x_t (M_{-1}=0);
//   y = sqrt(x * (M+1e-6)^-0.98 + 2) - sqrt(2)
// R9 = R8 (52.9us) with ONE change: y stores are non-temporal (nt flag,
// evict-first) so the 128MB y stream stops evicting x (131MB) from L2/L3.
// x then stays L3-resident across replays -> HBM reads ~vanish.
// Everything else identical to R8: DPP weighted scan, E=(I-b)/K carry, EPL=4,
// tile=256, 1 wave/row, prefetch depth 3, 2048 blocks x 256.

#define T_LEN 4000
#define TILE  256
#define NFULL (T_LEN / TILE)            // 15 full tiles
#define TAILL ((T_LEN - NFULL*TILE)/4)  // 40 active lanes in 160-elem tail

typedef float f32x4 __attribute__((ext_vector_type(4)));

constexpr double dpow(double b, int e) { double r = 1.0; for (int i = 0; i < e; ++i) r *= b; return r; }

// mov_dpp with old=0: masked-out / OOB lanes read 0.0f
template<int CTRL, int RMASK, bool BC>
__device__ __forceinline__ float dpp0(float x) {
    return __int_as_float(__builtin_amdgcn_update_dpp(
        0, __float_as_int(x), CTRL, RMASK, 0xf, BC));
}

__device__ __forceinline__ float pcen_y(float x, float M) {
    float p = __builtin_amdgcn_exp2f(-0.98f * __builtin_amdgcn_logf(M + 1e-6f));
    return sqrtf(fmaf(x, p, 2.0f)) - 1.41421356237309515f;
}

__global__ __launch_bounds__(256) void pcen_kernel(const float* __restrict__ x,
                                                   float* __restrict__ y) {
    const int wid  = threadIdx.x >> 6;
    const int lane = threadIdx.x & 63;
    const int row  = blockIdx.x * 4 + wid;

    const float S   = 0.025f, OMS = 0.975f;
    const float K1   = (float)dpow(0.975, 4);        // K = 0.975^4
    const float K2   = (float)dpow(0.975, 8);
    const float K4   = (float)dpow(0.975, 16);
    const float K8   = (float)dpow(0.975, 32);
    const float KT   = (float)dpow(0.975, 256);      // whole-tile decay
    const float invK = (float)(1.0 / dpow(0.975, 4));

    const float L2K = -0.14610279749811041f;         // log2(0.975^4)
    const float c  = __builtin_amdgcn_exp2f((float)lane * L2K);
    const float m1 = __builtin_amdgcn_exp2f((float)((lane & 15) + 1) * L2K);
    const float m2 = __builtin_amdgcn_exp2f((float)((lane & 31) + 1) * L2K);

    const float* __restrict__ xr = x + (size_t)row * T_LEN;
    float*       __restrict__ yr = y + (size_t)row * T_LEN;
    const int l4 = lane * 4;

    float M0 = 0.0f;

    // prefetch pipeline: 3 tiles in flight
    f32x4 p0 = *reinterpret_cast<const f32x4*>(xr + 0 * TILE + l4);
    f32x4 p1 = *reinterpret_cast<const f32x4*>(xr + 1 * TILE + l4);
    f32x4 p2 = *reinterpret_cast<const f32x4*>(xr + 2 * TILE + l4);

    #pragma unroll
    for (int t = 0; t < NFULL; ++t) {
        const f32x4 v = p0;
        p0 = p1; p1 = p2;                 // register rotation (renamed by unroll)
        if (t + 3 < NFULL)
            p2 = *reinterpret_cast<const f32x4*>(xr + (t + 3) * TILE + l4);

        // lane-local affine offset from M=0
        float b = S * v.x;
        b = fmaf(S, v.y, OMS * b);
        b = fmaf(S, v.z, OMS * b);
        b = fmaf(S, v.w, OMS * b);

        // 64-lane weighted inclusive scan (DPP, all in VALU pipe)
        float I = b, tv;
        tv = dpp0<0x111, 0xf, true >(I);  I = fmaf(K1, tv, I);   // row_shr:1
        tv = dpp0<0x112, 0xf, true >(I);  I = fmaf(K2, tv, I);   // row_shr:2
        tv = dpp0<0x114, 0xf, true >(I);  I = fmaf(K4, tv, I);   // row_shr:4
        tv = dpp0<0x118, 0xf, true >(I);  I = fmaf(K8, tv, I);   // row_shr:8
        tv = dpp0<0x142, 0xa, false>(I);  I = fmaf(m1, tv, I);   // bcast15 -> rows 1,3
        tv = dpp0<0x143, 0xc, false>(I);  I = fmaf(m2, tv, I);   // bcast31 -> rows 2,3

        // exclusive carry-in E = (I-b)/K, then replay 4 elements
        float M = fmaf(c, M0, (I - b) * invK);
        f32x4 o;
        M = fmaf(S, v.x, OMS * M);  o.x = pcen_y(v.x, M);
        M = fmaf(S, v.y, OMS * M);  o.y = pcen_y(v.y, M);
        M = fmaf(S, v.z, OMS * M);  o.z = pcen_y(v.z, M);
        M = fmaf(S, v.w, OMS * M);  o.w = pcen_y(v.w, M);
        __builtin_nontemporal_store(o, reinterpret_cast<f32x4*>(yr + t * TILE + l4));

        // cross-tile carry: inclusive total of lane 63
        const float Ilast = __int_as_float(
            __builtin_amdgcn_readlane(__float_as_int(I), 63));
        M0 = fmaf(KT, M0, Ilast);
    }

    // tail: 160 elements, lanes 0..39 active
    {
        const bool act = lane < TAILL;
        f32x4 v = {0.f, 0.f, 0.f, 0.f};
        if (act) v = *reinterpret_cast<const f32x4*>(xr + NFULL * TILE + l4);

        float b = S * v.x;
        b = fmaf(S, v.y, OMS * b);
        b = fmaf(S, v.z, OMS * b);
        b = fmaf(S, v.w, OMS * b);

        float I = b, tv;
        tv = dpp0<0x111, 0xf, true >(I);  I = fmaf(K1, tv, I);
        tv = dpp0<0x112, 0xf, true >(I);  I = fmaf(K2, tv, I);
        tv = dpp0<0x114, 0xf, true >(I);  I = fmaf(K4, tv, I);
        tv = dpp0<0x118, 0xf, true >(I);  I = fmaf(K8, tv, I);
        tv = dpp0<0x142, 0xa, false>(I);  I = fmaf(m1, tv, I);
        tv = dpp0<0x143, 0xc, false>(I);  I = fmaf(m2, tv, I);

        float M = fmaf(c, M0, (I - b) * invK);
        f32x4 o;
        M = fmaf(S, v.x, OMS * M);  o.x = pcen_y(v.x, M);
        M = fmaf(S, v.y, OMS * M);  o.y = pcen_y(v.y, M);
        M = fmaf(S, v.z, OMS * M);  o.z = pcen_y(v.z, M);
        M = fmaf(S, v.w, OMS * M);  o.w = pcen_y(v.w, M);
        if (act)
            __builtin_nontemporal_store(o, reinterpret_cast<f32x4*>(yr + NFULL * TILE + l4));
    }
}

extern "C" void kernel_launch(void* const* d_in, const int* in_sizes, int n_in,
                              void* d_out, int out_size, void* d_ws, size_t ws_size,
                              hipStream_t stream) {
    const float* x = (const float*)d_in[0];
    float* y       = (float*)d_out;
    pcen_kernel<<<8192 / 4, 256, 0, stream>>>(x, y);  // 2048 blocks, 4 rows/block
}

// Round 11
// 45.291 us; speedup vs baseline: 1.1676x; 1.0052x over previous
//
#include <hip/hip_runtime.h>

// PCEN [B=64,C=128,T=4000] f32: M_t = 0.975 M_{t-1} + 0.025 x_t (M_{-1}=0);
//   y = sqrt(x * (M+1e-6)^-0.98 + 2) - sqrt(2)
// R11 = exact revert to R9 (45.5us, passed). R10's sc1 streaming stores broke
// coherence (harness memset leaves d_out lines in L2; sc1 stores bypass L2 ->
// stale read-back). Pitfall recorded: sc1-alone stores are incoherent with
// normally-cached readers on gfx950.
// Structure: DPP weighted scan, E=(I-b)/K carry, EPL=4, tile=256, 1 wave/row,
// prefetch depth 3, __builtin_nontemporal_store (nt only) for y,
// 2048 blocks x 256.

#define T_LEN 4000
#define TILE  256
#define NFULL (T_LEN / TILE)            // 15 full tiles
#define TAILL ((T_LEN - NFULL*TILE)/4)  // 40 active lanes in 160-elem tail

typedef float f32x4 __attribute__((ext_vector_type(4)));

constexpr double dpow(double b, int e) { double r = 1.0; for (int i = 0; i < e; ++i) r *= b; return r; }

// mov_dpp with old=0: masked-out / OOB lanes read 0.0f
template<int CTRL, int RMASK, bool BC>
__device__ __forceinline__ float dpp0(float x) {
    return __int_as_float(__builtin_amdgcn_update_dpp(
        0, __float_as_int(x), CTRL, RMASK, 0xf, BC));
}

__device__ __forceinline__ float pcen_y(float x, float M) {
    float p = __builtin_amdgcn_exp2f(-0.98f * __builtin_amdgcn_logf(M + 1e-6f));
    return sqrtf(fmaf(x, p, 2.0f)) - 1.41421356237309515f;
}

__global__ __launch_bounds__(256) void pcen_kernel(const float* __restrict__ x,
                                                   float* __restrict__ y) {
    const int wid  = threadIdx.x >> 6;
    const int lane = threadIdx.x & 63;
    const int row  = blockIdx.x * 4 + wid;

    const float S   = 0.025f, OMS = 0.975f;
    const float K1   = (float)dpow(0.975, 4);        // K = 0.975^4
    const float K2   = (float)dpow(0.975, 8);
    const float K4   = (float)dpow(0.975, 16);
    const float K8   = (float)dpow(0.975, 32);
    const float KT   = (float)dpow(0.975, 256);      // whole-tile decay
    const float invK = (float)(1.0 / dpow(0.975, 4));

    const float L2K = -0.14610279749811041f;         // log2(0.975^4)
    const float c  = __builtin_amdgcn_exp2f((float)lane * L2K);
    const float m1 = __builtin_amdgcn_exp2f((float)((lane & 15) + 1) * L2K);
    const float m2 = __builtin_amdgcn_exp2f((float)((lane & 31) + 1) * L2K);

    const float* __restrict__ xr = x + (size_t)row * T_LEN;
    float*       __restrict__ yr = y + (size_t)row * T_LEN;
    const int l4 = lane * 4;

    float M0 = 0.0f;

    // prefetch pipeline: 3 tiles in flight
    f32x4 p0 = *reinterpret_cast<const f32x4*>(xr + 0 * TILE + l4);
    f32x4 p1 = *reinterpret_cast<const f32x4*>(xr + 1 * TILE + l4);
    f32x4 p2 = *reinterpret_cast<const f32x4*>(xr + 2 * TILE + l4);

    #pragma unroll
    for (int t = 0; t < NFULL; ++t) {
        const f32x4 v = p0;
        p0 = p1; p1 = p2;                 // register rotation (renamed by unroll)
        if (t + 3 < NFULL)
            p2 = *reinterpret_cast<const f32x4*>(xr + (t + 3) * TILE + l4);

        // lane-local affine offset from M=0
        float b = S * v.x;
        b = fmaf(S, v.y, OMS * b);
        b = fmaf(S, v.z, OMS * b);
        b = fmaf(S, v.w, OMS * b);

        // 64-lane weighted inclusive scan (DPP, all in VALU pipe)
        float I = b, tv;
        tv = dpp0<0x111, 0xf, true >(I);  I = fmaf(K1, tv, I);   // row_shr:1
        tv = dpp0<0x112, 0xf, true >(I);  I = fmaf(K2, tv, I);   // row_shr:2
        tv = dpp0<0x114, 0xf, true >(I);  I = fmaf(K4, tv, I);   // row_shr:4
        tv = dpp0<0x118, 0xf, true >(I);  I = fmaf(K8, tv, I);   // row_shr:8
        tv = dpp0<0x142, 0xa, false>(I);  I = fmaf(m1, tv, I);   // bcast15 -> rows 1,3
        tv = dpp0<0x143, 0xc, false>(I);  I = fmaf(m2, tv, I);   // bcast31 -> rows 2,3

        // exclusive carry-in E = (I-b)/K, then replay 4 elements
        float M = fmaf(c, M0, (I - b) * invK);
        f32x4 o;
        M = fmaf(S, v.x, OMS * M);  o.x = pcen_y(v.x, M);
        M = fmaf(S, v.y, OMS * M);  o.y = pcen_y(v.y, M);
        M = fmaf(S, v.z, OMS * M);  o.z = pcen_y(v.z, M);
        M = fmaf(S, v.w, OMS * M);  o.w = pcen_y(v.w, M);
        __builtin_nontemporal_store(o, reinterpret_cast<f32x4*>(yr + t * TILE + l4));

        // cross-tile carry: inclusive total of lane 63
        const float Ilast = __int_as_float(
            __builtin_amdgcn_readlane(__float_as_int(I), 63));
        M0 = fmaf(KT, M0, Ilast);
    }

    // tail: 160 elements, lanes 0..39 active
    {
        const bool act = lane < TAILL;
        f32x4 v = {0.f, 0.f, 0.f, 0.f};
        if (act) v = *reinterpret_cast<const f32x4*>(xr + NFULL * TILE + l4);

        float b = S * v.x;
        b = fmaf(S, v.y, OMS * b);
        b = fmaf(S, v.z, OMS * b);
        b = fmaf(S, v.w, OMS * b);

        float I = b, tv;
        tv = dpp0<0x111, 0xf, true >(I);  I = fmaf(K1, tv, I);
        tv = dpp0<0x112, 0xf, true >(I);  I = fmaf(K2, tv, I);
        tv = dpp0<0x114, 0xf, true >(I);  I = fmaf(K4, tv, I);
        tv = dpp0<0x118, 0xf, true >(I);  I = fmaf(K8, tv, I);
        tv = dpp0<0x142, 0xa, false>(I);  I = fmaf(m1, tv, I);
        tv = dpp0<0x143, 0xc, false>(I);  I = fmaf(m2, tv, I);

        float M = fmaf(c, M0, (I - b) * invK);
        f32x4 o;
        M = fmaf(S, v.x, OMS * M);  o.x = pcen_y(v.x, M);
        M = fmaf(S, v.y, OMS * M);  o.y = pcen_y(v.y, M);
        M = fmaf(S, v.z, OMS * M);  o.z = pcen_y(v.z, M);
        M = fmaf(S, v.w, OMS * M);  o.w = pcen_y(v.w, M);
        if (act)
            __builtin_nontemporal_store(o, reinterpret_cast<f32x4*>(yr + NFULL * TILE + l4));
    }
}

extern "C" void kernel_launch(void* const* d_in, const int* in_sizes, int n_in,
                              void* d_out, int out_size, void* d_ws, size_t ws_size,
                              hipStream_t stream) {
    const float* x = (const float*)d_in[0];
    float* y       = (float*)d_out;
    pcen_kernel<<<8192 / 4, 256, 0, stream>>>(x, y);  // 2048 blocks, 4 rows/block
}